// Round 1
// baseline (899.916 us; speedup 1.0000x reference)
//
#include <hip/hip_runtime.h>

// ConvLSTM cell, MI355X. Single implicit-GEMM over concat(x,h) channels with
// bf16 MFMA (32x32x16), fused in-register LSTM epilogue.
//
// Sizes: B=256, CIN=CH=256, HW=16, K=3. S=256 spatial. IC total = 512.
// GEMM: M=65536 (b,s), N=1024 (4 gates x 256 ch), K=4608 (512 ic x 9 taps).

typedef __bf16 bf16x8 __attribute__((ext_vector_type(8)));
typedef float f32x16 __attribute__((ext_vector_type(16)));

#define XH_ELTS   33554432u   // 256 b * 16 icblk * 256 s * 32 c
#define WT_ELTS   4718592u    // 9216 chunks * 512
#define OUT_HALF  16777216u   // B*CH*S

// ---------------------------------------------------------------------------
// P1a: x,h (NCHW fp32) -> xh bf16, layout [b][icblk(16)][s(256)][c(32)]
// icblk 0..7 = x channels, 8..15 = h channels. One block per (b, icblk).
__global__ __launch_bounds__(256) void xh_transform(
    const float* __restrict__ x, const float* __restrict__ hh,
    __bf16* __restrict__ xh)
{
    int blk = blockIdx.x;              // b*16 + ib
    int b = blk >> 4, ib = blk & 15;
    const float* src = (ib < 8) ? (x  + ((size_t)(b*256 + ib*32)) * 256)
                                : (hh + ((size_t)(b*256 + (ib-8)*32)) * 256);
    int t = threadIdx.x;               // t == spatial s
    uint32_t w[16];
#pragma unroll
    for (int i = 0; i < 16; ++i) {
        __bf16 lo = (__bf16)src[(size_t)(2*i  )*256 + t];   // coalesced per i
        __bf16 hi = (__bf16)src[(size_t)(2*i+1)*256 + t];
        w[i] = (uint32_t)__builtin_bit_cast(unsigned short, lo)
             | ((uint32_t)__builtin_bit_cast(unsigned short, hi) << 16);
    }
    uint4* dst = (uint4*)(xh + (size_t)blk*8192 + (size_t)t*32);
#pragma unroll
    for (int i = 0; i < 4; ++i)
        dst[i] = uint4{w[4*i], w[4*i+1], w[4*i+2], w[4*i+3]};
}

// ---------------------------------------------------------------------------
// P1b: Wx,Wh (OIHW fp32) -> Wt bf16 in A-fragment order.
// Chunk = (((pos*8+cb)*4+fg)*16 + icblk)*2 + half ; chunk holds 64 lanes x 8 bf16.
// A-frag layout (32x32x16): row = lane&31, k = (lane>>5)*8 + j.
// oc' row interleaves gates: ch8 = row>>2, gate = row&3,
// oc = gate*256 + cb*32 + fg*8 + ch8.  ic = icblk*32 + half*16 + (lane>>5)*8 + j.
__global__ __launch_bounds__(256) void w_transform(
    const float* __restrict__ Wx, const float* __restrict__ Wh,
    __bf16* __restrict__ Wt)
{
    int idx  = blockIdx.x * 256 + threadIdx.x;   // 589824 total
    int lane = idx & 63;
    int chunk = idx >> 6;                        // 9216 chunks
    int half  = chunk & 1;
    int icblk = (chunk >> 1) & 15;
    int fg    = (chunk >> 5) & 3;
    int cb    = (chunk >> 7) & 7;
    int pos   = chunk >> 10;                     // ky*3+kx
    int row = lane & 31, hl = lane >> 5;
    int gate = row & 3, ch8 = row >> 2;
    int oc  = gate*256 + cb*32 + fg*8 + ch8;
    int ic0 = icblk*32 + half*16 + hl*8;
    bf16x8 v;
#pragma unroll
    for (int j = 0; j < 8; ++j) {
        int ic = ic0 + j;
        float w = (ic < 256) ? Wx[((size_t)oc*256 + ic      )*9 + pos]
                             : Wh[((size_t)oc*256 + (ic-256))*9 + pos];
        v[j] = (__bf16)w;
    }
    *(bf16x8*)(Wt + (size_t)chunk*512 + (size_t)lane*8) = v;
}

// ---------------------------------------------------------------------------
// Main kernel: one block per (b, cb). cb = bid&7 -> same-weight blocks land on
// the same XCD (round-robin dispatch heuristic) so the 1.2 MB weight slice is
// L2-resident. Block tile: 128 oc' (4 gates x 32 ch) x 256 spatial.
// 4 waves in 2x2: wm = m-half (128 rows), wn = oc-half (2 of 4 fragments).
// LDS: double-buffered padded plane [18][18][32ic] bf16, zero border = SAME
// padding, XOR-swizzled (byte ^= (p&7)<<4) for conflict-free ds_read_b128.
__global__ __launch_bounds__(256, 2) void convlstm_main(
    const __bf16* __restrict__ xh, const __bf16* __restrict__ Wt,
    const float* __restrict__ bh,  const float* __restrict__ cin,
    const float* __restrict__ Wci, const float* __restrict__ Wcf,
    const float* __restrict__ Wco, float* __restrict__ out)
{
    int bid = blockIdx.x;
    int cb  = bid & 7;
    int b   = bid >> 3;
    int tid = threadIdx.x;
    int lane = tid & 63;
    int wid  = tid >> 6;
    int l31  = lane & 31;
    int hl   = lane >> 5;
    int wm = wid & 1, wn = wid >> 1;

    __shared__ __align__(16) unsigned short lds[2][18*18*32];

    // zero both buffers (borders must stay 0 for SAME padding)
    {
        uint32_t* p = (uint32_t*)&lds[0][0];
        for (int i = tid; i < (2*18*18*32)/2; i += 256) p[i] = 0u;
    }

    // accumulators init with bias bh[oc] (bias enters the gate sum once)
    f32x16 acc[4][2];
#pragma unroll
    for (int f = 0; f < 2; ++f) {
        int fg = wn*2 + f;
        f32x16 v;
#pragma unroll
        for (int r = 0; r < 16; ++r) {
            int gate = r & 3, q = r >> 2;
            v[r] = bh[gate*256 + cb*32 + fg*8 + 2*q + hl];
        }
        acc[0][f] = v; acc[1][f] = v; acc[2][f] = v; acc[3][f] = v;
    }
    __syncthreads();

    // staging: thread t <-> spatial s; padded position p_pad = (y+1)*18+(x+1)
    const int s = tid;
    const int p_pad = ((s >> 4) + 1)*18 + (s & 15) + 1;
    const uint32_t wby  = (uint32_t)p_pad * 64u;
    const uint32_t wswz = ((uint32_t)(p_pad & 7)) << 4;
    const __bf16* xb = xh + (size_t)b * (16*8192);

    // stage ic-block 0 into buffer 0
    {
        const uint4* g = (const uint4*)(xb + (size_t)s*32);
        uint4 a0=g[0], a1=g[1], a2=g[2], a3=g[3];
        char* p0 = (char*)&lds[0][0];
        *(uint4*)(p0 + ((wby+ 0)^wswz)) = a0;
        *(uint4*)(p0 + ((wby+16)^wswz)) = a1;
        *(uint4*)(p0 + ((wby+32)^wswz)) = a2;
        *(uint4*)(p0 + ((wby+48)^wswz)) = a3;
    }
    __syncthreads();

    // per-wave B-frag spatial bases
    int my[4], mx[4];
#pragma unroll
    for (int mf = 0; mf < 4; ++mf) {
        int m = wm*128 + mf*32 + l31;
        my[mf] = m >> 4; mx[mf] = m & 15;
    }

    for (int ib = 0; ib < 16; ++ib) {
        const int cur = ib & 1;
        // issue next-block staging loads BEFORE the compute phase (latency
        // hides under 144 MFMAs); write to other buffer after the phase.
        uint4 a0, a1, a2, a3;
        if (ib < 15) {
            const uint4* g = (const uint4*)(xb + (size_t)(ib+1)*8192 + (size_t)s*32);
            a0=g[0]; a1=g[1]; a2=g[2]; a3=g[3];
        }
        const char* rb = (const char*)&lds[cur][0];
#pragma unroll
        for (int pos = 0; pos < 9; ++pos) {
            const int dky = pos/3, dkx = pos%3;
#pragma unroll
            for (int half = 0; half < 2; ++half) {
                bf16x8 afr[2];
#pragma unroll
                for (int f = 0; f < 2; ++f) {
                    int fg = wn*2 + f;
                    size_t chunk = ((size_t)((pos*8 + cb)*4 + fg))*32
                                 + (size_t)(ib*2 + half);
                    afr[f] = *(const bf16x8*)(Wt + chunk*512 + (size_t)lane*8);
                }
                bf16x8 bfr[4];
#pragma unroll
                for (int mf = 0; mf < 4; ++mf) {
                    int p = (my[mf] + dky)*18 + mx[mf] + dkx;
                    uint32_t byte = (((uint32_t)p)*64u
                                   + (uint32_t)(half*32 + hl*16))
                                   ^ (((uint32_t)(p & 7)) << 4);
                    bfr[mf] = *(const bf16x8*)(rb + byte);
                }
#pragma unroll
                for (int mf = 0; mf < 4; ++mf)
#pragma unroll
                    for (int f = 0; f < 2; ++f)
                        acc[mf][f] = __builtin_amdgcn_mfma_f32_32x32x16_bf16(
                            afr[f], bfr[mf], acc[mf][f], 0, 0, 0);
            }
        }
        if (ib < 15) {
            char* pw = (char*)&lds[cur ^ 1][0];
            *(uint4*)(pw + ((wby+ 0)^wswz)) = a0;
            *(uint4*)(pw + ((wby+16)^wswz)) = a1;
            *(uint4*)(pw + ((wby+32)^wswz)) = a2;
            *(uint4*)(pw + ((wby+48)^wswz)) = a3;
        }
        __syncthreads();
    }

    // fused LSTM epilogue, fully in-register. D layout (32x32):
    // col = lane&31 (spatial m), row = (r&3) + 8*(r>>2) + 4*hl ->
    // gate = r&3, ch8 = 2*(r>>2)+hl. r = 4*q + gate.
    float* outh = out;
    float* outc = out + (size_t)OUT_HALF;
    const size_t bOff = (size_t)b * (256*256);
#pragma unroll
    for (int mf = 0; mf < 4; ++mf) {
        int m = wm*128 + mf*32 + l31;
#pragma unroll
        for (int f = 0; f < 2; ++f) {
            int fg = wn*2 + f;
#pragma unroll
            for (int q = 0; q < 4; ++q) {
                int ch = cb*32 + fg*8 + 2*q + hl;
                size_t pidx = (size_t)ch*256 + (size_t)m;
                size_t idx  = bOff + pidx;
                float cv = cin[idx];
                float pi = acc[mf][f][4*q+0];
                float pf = acc[mf][f][4*q+1];
                float pc = acc[mf][f][4*q+2];
                float po = acc[mf][f][4*q+3];
                float it = 1.f/(1.f + __expf(-(pi + Wci[pidx]*cv)));
                float ft = 1.f/(1.f + __expf(-(pf + Wcf[pidx]*cv)));
                float tc = 1.f - 2.f/(1.f + __expf(2.f*pc));
                float ct = ft*cv + it*tc;
                float ot = 1.f/(1.f + __expf(-(po + Wco[pidx]*ct)));
                float th = 1.f - 2.f/(1.f + __expf(2.f*ct));
                outh[idx] = ot*th;
                outc[idx] = ct;
            }
        }
    }
}

// ---------------------------------------------------------------------------
extern "C" void kernel_launch(void* const* d_in, const int* in_sizes, int n_in,
                              void* d_out, int out_size, void* d_ws, size_t ws_size,
                              hipStream_t stream)
{
    const float* x   = (const float*)d_in[0];
    const float* h   = (const float*)d_in[1];
    const float* c   = (const float*)d_in[2];
    const float* Wx  = (const float*)d_in[3];
    const float* Wh  = (const float*)d_in[4];
    const float* bh  = (const float*)d_in[5];
    const float* Wci = (const float*)d_in[6];
    const float* Wcf = (const float*)d_in[7];
    const float* Wco = (const float*)d_in[8];
    float* out = (float*)d_out;

    __bf16* xh = (__bf16*)d_ws;                 // 67,108,864 B
    __bf16* Wt = xh + (size_t)XH_ELTS;          // + 9,437,184 B = 76.5 MB total

    hipLaunchKernelGGL(xh_transform, dim3(4096), dim3(256), 0, stream, x, h, xh);
    hipLaunchKernelGGL(w_transform,  dim3(2304), dim3(256), 0, stream, Wx, Wh, Wt);
    hipLaunchKernelGGL(convlstm_main, dim3(2048), dim3(256), 0, stream,
                       xh, Wt, bh, c, Wci, Wcf, Wco, out);
}